// Round 2
// baseline (216.618 us; speedup 1.0000x reference)
//
#include <hip/hip_runtime.h>

typedef __attribute__((ext_vector_type(8))) short short8;
typedef __attribute__((ext_vector_type(4))) float floatx4;

#define TOKENS 2048
#define IN_F   4096
#define OUT_F  4096
#define NITER  20

#define INV_2PI 0.15915494309189535f
#define TWO_PI  6.283185307179586f

// round-to-nearest-even f32 -> bf16 bits
__device__ __forceinline__ unsigned short f2bf(float f) {
    unsigned int u = __builtin_bit_cast(unsigned int, f);
    u += 0x7fffu + ((u >> 16) & 1u);
    return (unsigned short)(u >> 16);
}

// one fractal step in REVOLUTION units: v' = a*v + (b/2pi)*sin(2pi*v)
__device__ __forceinline__ void step4(float4& v, float a, float bc) {
    v.x = __builtin_fmaf(bc, __builtin_amdgcn_sinf(v.x), a * v.x);
    v.y = __builtin_fmaf(bc, __builtin_amdgcn_sinf(v.y), a * v.y);
    v.z = __builtin_fmaf(bc, __builtin_amdgcn_sinf(v.z), a * v.z);
    v.w = __builtin_fmaf(bc, __builtin_amdgcn_sinf(v.w), a * v.w);
}

#define WBLOCKS (OUT_F * IN_F / 8 / 256)   // 8192
#define XBLOCKS (TOKENS * IN_F / 8 / 256)  // 4096

// Fused: blocks [0,8192) transcribe seed->w_bf (20 iters); [8192,12288) cast x->x_bf.
__global__ __launch_bounds__(256) void transcribe_fused_kernel(
    const float4* __restrict__ seed, const float4* __restrict__ xin,
    const float* __restrict__ da, const float* __restrict__ db,
    short8* __restrict__ w_out, short8* __restrict__ x_out)
{
    const int b = blockIdx.x;
    short8 o;
    if (b < WBLOCKS) {
        int i = b * 256 + threadIdx.x;
        float4 u = seed[2 * i];
        float4 v = seed[2 * i + 1];
        u.x *= INV_2PI; u.y *= INV_2PI; u.z *= INV_2PI; u.w *= INV_2PI;
        v.x *= INV_2PI; v.y *= INV_2PI; v.z *= INV_2PI; v.w *= INV_2PI;
#pragma unroll
        for (int t = 0; t < NITER; t++) {
            float a = da[t], bc = db[t] * INV_2PI;
            step4(u, a, bc);
            step4(v, a, bc);
        }
        o[0] = (short)f2bf(u.x * TWO_PI); o[1] = (short)f2bf(u.y * TWO_PI);
        o[2] = (short)f2bf(u.z * TWO_PI); o[3] = (short)f2bf(u.w * TWO_PI);
        o[4] = (short)f2bf(v.x * TWO_PI); o[5] = (short)f2bf(v.y * TWO_PI);
        o[6] = (short)f2bf(v.z * TWO_PI); o[7] = (short)f2bf(v.w * TWO_PI);
        w_out[i] = o;
    } else {
        int i = (b - WBLOCKS) * 256 + threadIdx.x;
        float4 u = xin[2 * i];
        float4 v = xin[2 * i + 1];
        o[0] = (short)f2bf(u.x); o[1] = (short)f2bf(u.y);
        o[2] = (short)f2bf(u.z); o[3] = (short)f2bf(u.w);
        o[4] = (short)f2bf(v.x); o[5] = (short)f2bf(v.y);
        o[6] = (short)f2bf(v.z); o[7] = (short)f2bf(v.w);
        x_out[i] = o;
    }
}

// async 16B global -> LDS (per-lane global addr, linear wave-uniform LDS dest)
__device__ __forceinline__ void g2l16(const ushort* g, ushort* l) {
    __builtin_amdgcn_global_load_lds(
        (const __attribute__((address_space(1))) unsigned int*)g,
        (__attribute__((address_space(3))) unsigned int*)l, 16, 0, 0);
}

// ---------------------------------------------------------------------------
// GEMM: C[M,N] = A[M,K] * B[N,K]^T + bias[N];  A,B bf16 bits, C f32.
//
// Round-1 counters: MfmaUtil 38%, conflicts 0, HBM 29% -> LDS-BW-bound:
// per tile 128 KiB ds_read + 48 KiB stage-write = 176 KiB / 85 B/cyc = 2070cy
// vs 1242cy MFMA.  Fix: raise MFMA per LDS byte via 128x64 wave-tiles WITHOUT
// shrinking the 256-block grid: 8 waves = 2x2 spatial x 2 K-GROUPS.  Group g
// (waves 4g..4g+3) reads only k-slice [32g,32g+32) of each BK=64 tile ->
// 12 b128 reads feed 32 MFMAs/wave (0.375 reads/MFMA vs 0.5 before); per-tile
// LDS = 96 KiB read + 48 KiB write = 144 KiB -> ~1694cy floor (73% ceiling).
// Partial accumulators of the two K-groups are summed via LDS in the epilogue
// (128 KiB round-trip, reuses ring memory, ~1.3 us).
//
// Pipeline (UNCHANGED, verified round-1): 3-deep LDS ring (3 x 48 KiB),
// counted vmcnt (6 loads/wave/tile; main loop waits vmcnt(12), tail 12/6/0 —
// never drains in-loop), raw s_barrier x2 per tile, stage-after-lgkm0+barrier,
// setprio around MFMA, sched_barrier between stage and MFMA.
// LDS swizzle (verified, 0 conflicts): 128B rows, physical 16B seg p of row r
// holds logical seg p ^ (r&7); pre-swizzled global source, linear LDS dest.
//
// XCD swizzle flipped to bn-stripes: each XCD owns 4 B-panels (4 MiB,
// L2-resident) x all 8 bm; A streams.  (Round-1 bm-stripes streamed all of B
// through every XCD L2: FETCH 84 -> 139 MB.  Expect ~100-110 MB now.)
// ---------------------------------------------------------------------------
#define BK     64
#define BM     256
#define BN     128
#define NT     (IN_F / BK)        // 64 K-tiles
#define ASLOT  (BM * BK)          // 16384 ushorts = 32 KiB
#define BSLOT  (BN * BK)          //  8192 ushorts = 16 KiB
#define LDS_BYTES (3 * (ASLOT + BSLOT) * 2)   // 147456 B = 144 KiB

__global__ __launch_bounds__(512, 2) void gemm_bt_kernel(
    const ushort* __restrict__ A,
    const ushort* __restrict__ B,
    const float* __restrict__ bias,
    float* __restrict__ C)
{
    extern __shared__ ushort lds[];
    ushort* As = lds;                  // [3][ASLOT]
    ushort* Bs = lds + 3 * ASLOT;      // [3][BSLOT]

    const int tid  = threadIdx.x;
    const int lane = tid & 63;
    const int wid  = tid >> 6;         // 0..7
    const int g    = wid >> 2;         // K-group: 0 -> k[0,32), 1 -> k[32,64)
    const int w2   = wid & 3;          // spatial wave 2x2
    const int wm   = (w2 >> 1) << 7;   // 0/128
    const int wn   = (w2 & 1) << 6;    // 0/64
    const int fm   = lane & 15;
    const int q    = lane >> 4;        // 0..3

    // XCD-aware swizzle, bn-stripes: xcd = bid&7 owns bn in {4*xcd..4*xcd+3},
    // bm = 0..7 (bijective over the 256-block grid).
    const int bid = blockIdx.x;
    const int jj  = bid >> 3;                  // 0..31
    const int bn  = (bid & 7) * 4 + (jj & 3);  // 0..31
    const int bm  = jj >> 2;                   // 0..7

    // staging: wave-instr covers 64 consecutive 16B chunks (8 rows x 8 segs);
    // lane = (row&7)*8 + pseg; global source segment = pseg ^ (row&7).
    const int gcol = (((lane & 7) ^ (lane >> 3)) << 3);

    const ushort* gA = A + (size_t)(bm * BM) * IN_F;
    const ushort* gB = B + (size_t)(bn * BN) * IN_F;

    floatx4 acc[8][4];
#pragma unroll
    for (int i = 0; i < 8; i++)
#pragma unroll
        for (int j = 0; j < 4; j++)
            acc[i][j] = (floatx4){0.f, 0.f, 0.f, 0.f};

    // A-slab: 2048 chunks -> 4 wave-instrs/wave; B-slab: 1024 -> 2/wave.
    // 6 VMEM instrs per wave per tile (vmcnt counts these).
#define STAGE(k0v, sl)                                                        \
    {                                                                         \
        _Pragma("unroll")                                                     \
        for (int u = 0; u < 4; u++) {                                         \
            const int cb = ((u << 3) | wid) << 6;                             \
            const int r  = (cb >> 3) + (lane >> 3);                           \
            g2l16(gA + (size_t)r * IN_F + (k0v) + gcol,                       \
                  As + (sl) * ASLOT + cb * 8 + lane * 8);                     \
        }                                                                     \
        _Pragma("unroll")                                                     \
        for (int u = 0; u < 2; u++) {                                         \
            const int cb = ((u << 3) | wid) << 6;                             \
            const int r  = (cb >> 3) + (lane >> 3);                           \
            g2l16(gB + (size_t)r * IN_F + (k0v) + gcol,                       \
                  Bs + (sl) * BSLOT + cb * 8 + lane * 8);                     \
        }                                                                     \
    }

    // 12 x ds_read_b128: this wave's K-slice (= group g) of slot sl.
    // Same verified swizzled pattern as round-1 (slice index s_ := g).
#define LOADFRAG(sl)                                                          \
    const int sa = (((q + 4 * g) & 7) ^ (fm & 7)) << 3;                       \
    _Pragma("unroll")                                                         \
    for (int i = 0; i < 8; i++)                                               \
        af[i] = *(const short8*)(As + (sl) * ASLOT + (wm + i * 16 + fm) * BK + sa); \
    _Pragma("unroll")                                                         \
    for (int j = 0; j < 4; j++)                                               \
        bf[j] = *(const short8*)(Bs + (sl) * BSLOT + (wn + j * 16 + fm) * BK + sa);

#define MFMA32()                                                              \
    __builtin_amdgcn_s_setprio(1);                                            \
    _Pragma("unroll")                                                         \
    for (int i = 0; i < 8; i++)                                               \
        _Pragma("unroll")                                                     \
        for (int j = 0; j < 4; j++)                                           \
            acc[i][j] = __builtin_amdgcn_mfma_f32_16x16x32_bf16(              \
                af[i], bf[j], acc[i][j], 0, 0, 0);                            \
    __builtin_amdgcn_s_setprio(0);

#define TILE_MAIN(vm, sl, k3)                                                 \
    {                                                                         \
        asm volatile("s_waitcnt vmcnt(" #vm ")" ::: "memory");                \
        __builtin_amdgcn_s_barrier();                                         \
        short8 af[8], bf[4];                                                  \
        LOADFRAG(sl);                                                         \
        asm volatile("s_waitcnt lgkmcnt(0)" ::: "memory");                    \
        __builtin_amdgcn_s_barrier();                                         \
        STAGE(k3, sl);                                                        \
        __builtin_amdgcn_sched_barrier(0);                                    \
        MFMA32();                                                             \
    }

#define TILE_TAIL(vm, sl)                                                     \
    {                                                                         \
        asm volatile("s_waitcnt vmcnt(" #vm ")" ::: "memory");                \
        __builtin_amdgcn_s_barrier();                                         \
        short8 af[8], bf[4];                                                  \
        LOADFRAG(sl);                                                         \
        MFMA32();                                                             \
    }

    // prologue: fill the 3-deep ring (18 loads/wave in flight)
    STAGE(0 * BK, 0);
    STAGE(1 * BK, 1);
    STAGE(2 * BK, 2);

    int st   = 0;
    int kpre = 3 * BK;
#pragma unroll 1
    for (int t = 0; t <= NT - 4; ++t) {        // t = 0..60, stages tiles 3..63
        TILE_MAIN(12, st, kpre);
        kpre += BK;
        st = (st == 2) ? 0 : st + 1;
    }
    // tail: tiles 61 (slot1), 62 (slot2), 63 (slot0); drain 12 -> 6 -> 0
    TILE_TAIL(12, 1);
    TILE_TAIL(6, 2);
    TILE_TAIL(0, 0);

#undef STAGE
#undef LOADFRAG
#undef MFMA32
#undef TILE_MAIN
#undef TILE_TAIL

    // -----------------------------------------------------------------------
    // K-split reduction: group1 parks its partials in LDS (ring memory is
    // dead now), group0 adds them, applies bias, stores C.
    // Layout [frag 0..127][lane] in floatx4 units: linear 16B/lane sweep.
    // -----------------------------------------------------------------------
    __syncthreads();                       // all ring reads done before reuse
    floatx4* red = (floatx4*)lds;          // 128 KiB used of 144
    if (g == 1) {
#pragma unroll
        for (int i = 0; i < 8; i++)
#pragma unroll
            for (int j = 0; j < 4; j++)
                red[(size_t)(w2 * 32 + i * 4 + j) * 64 + lane] = acc[i][j];
    }
    __syncthreads();
    if (g == 0) {
        // epilogue: C/D layout col = lane&15, row = (lane>>4)*4 + reg  [m89]
        const int cn = lane & 15;
        const int cm = (lane >> 4) << 2;
        float bv[4];
#pragma unroll
        for (int j = 0; j < 4; j++)
            bv[j] = bias[bn * BN + wn + j * 16 + cn];
#pragma unroll
        for (int i = 0; i < 8; i++) {
#pragma unroll
            for (int j = 0; j < 4; j++) {
                floatx4 p = red[(size_t)(w2 * 32 + i * 4 + j) * 64 + lane];
#pragma unroll
                for (int r = 0; r < 4; r++) acc[i][j][r] += p[r];
            }
#pragma unroll
            for (int r = 0; r < 4; r++) {
                int m = bm * BM + wm + i * 16 + cm + r;
                float* crow = C + (size_t)m * OUT_F + bn * BN + wn + cn;
#pragma unroll
                for (int j = 0; j < 4; j++)
                    crow[j * 16] = acc[i][j][r] + bv[j];
            }
        }
    }
}

extern "C" void kernel_launch(void* const* d_in, const int* in_sizes, int n_in,
                              void* d_out, int out_size, void* d_ws, size_t ws_size,
                              hipStream_t stream) {
    const float* x    = (const float*)d_in[0];   // [2048, 4096]
    const float* seed = (const float*)d_in[1];   // [4096, 4096]
    const float* da   = (const float*)d_in[2];   // [20]
    const float* db   = (const float*)d_in[3];   // [20]
    const float* bias = (const float*)d_in[4];   // [4096]
    float* out        = (float*)d_out;           // [2048, 4096]

    ushort* w_bf = (ushort*)d_ws;                      // 32 MiB
    ushort* x_bf = w_bf + (size_t)OUT_F * IN_F;        // 16 MiB

    // allow 144 KiB dynamic LDS (one-time host-side attribute; not a stream op)
    static bool lds_attr_set = false;
    if (!lds_attr_set) {
        hipFuncSetAttribute(reinterpret_cast<const void*>(gemm_bt_kernel),
                            hipFuncAttributeMaxDynamicSharedMemorySize,
                            LDS_BYTES);
        lds_attr_set = true;
    }

    transcribe_fused_kernel<<<WBLOCKS + XBLOCKS, 256, 0, stream>>>(
        (const float4*)seed, (const float4*)x, da, db,
        (short8*)w_bf, (short8*)x_bf);

    gemm_bt_kernel<<<dim3(32 * 8), dim3(512), LDS_BYTES, stream>>>(
        x_bf, w_bf, bias, out);
}

// Round 3
// 214.058 us; speedup vs baseline: 1.0120x; 1.0120x over previous
//
#include <hip/hip_runtime.h>

typedef __attribute__((ext_vector_type(8))) short short8;
typedef __attribute__((ext_vector_type(4))) float floatx4;

#define TOKENS 2048
#define IN_F   4096
#define OUT_F  4096
#define NITER  20

#define INV_2PI 0.15915494309189535f
#define TWO_PI  6.283185307179586f

// round-to-nearest-even f32 -> bf16 bits
__device__ __forceinline__ unsigned short f2bf(float f) {
    unsigned int u = __builtin_bit_cast(unsigned int, f);
    u += 0x7fffu + ((u >> 16) & 1u);
    return (unsigned short)(u >> 16);
}

// one fractal step in REVOLUTION units: v' = a*v + (b/2pi)*sin(2pi*v)
__device__ __forceinline__ void step4(float4& v, float a, float bc) {
    v.x = __builtin_fmaf(bc, __builtin_amdgcn_sinf(v.x), a * v.x);
    v.y = __builtin_fmaf(bc, __builtin_amdgcn_sinf(v.y), a * v.y);
    v.z = __builtin_fmaf(bc, __builtin_amdgcn_sinf(v.z), a * v.z);
    v.w = __builtin_fmaf(bc, __builtin_amdgcn_sinf(v.w), a * v.w);
}

#define WBLOCKS (OUT_F * IN_F / 8 / 256)   // 8192
#define XBLOCKS (TOKENS * IN_F / 8 / 256)  // 4096

// Fused: blocks [0,8192) transcribe seed->w_bf (20 iters); [8192,12288) cast x->x_bf.
__global__ __launch_bounds__(256) void transcribe_fused_kernel(
    const float4* __restrict__ seed, const float4* __restrict__ xin,
    const float* __restrict__ da, const float* __restrict__ db,
    short8* __restrict__ w_out, short8* __restrict__ x_out)
{
    const int b = blockIdx.x;
    short8 o;
    if (b < WBLOCKS) {
        int i = b * 256 + threadIdx.x;
        float4 u = seed[2 * i];
        float4 v = seed[2 * i + 1];
        u.x *= INV_2PI; u.y *= INV_2PI; u.z *= INV_2PI; u.w *= INV_2PI;
        v.x *= INV_2PI; v.y *= INV_2PI; v.z *= INV_2PI; v.w *= INV_2PI;
#pragma unroll
        for (int t = 0; t < NITER; t++) {
            float a = da[t], bc = db[t] * INV_2PI;
            step4(u, a, bc);
            step4(v, a, bc);
        }
        o[0] = (short)f2bf(u.x * TWO_PI); o[1] = (short)f2bf(u.y * TWO_PI);
        o[2] = (short)f2bf(u.z * TWO_PI); o[3] = (short)f2bf(u.w * TWO_PI);
        o[4] = (short)f2bf(v.x * TWO_PI); o[5] = (short)f2bf(v.y * TWO_PI);
        o[6] = (short)f2bf(v.z * TWO_PI); o[7] = (short)f2bf(v.w * TWO_PI);
        w_out[i] = o;
    } else {
        int i = (b - WBLOCKS) * 256 + threadIdx.x;
        float4 u = xin[2 * i];
        float4 v = xin[2 * i + 1];
        o[0] = (short)f2bf(u.x); o[1] = (short)f2bf(u.y);
        o[2] = (short)f2bf(u.z); o[3] = (short)f2bf(u.w);
        o[4] = (short)f2bf(v.x); o[5] = (short)f2bf(v.y);
        o[6] = (short)f2bf(v.z); o[7] = (short)f2bf(v.w);
        x_out[i] = o;
    }
}

// async 16B global -> LDS (per-lane global addr, linear wave-uniform LDS dest)
__device__ __forceinline__ void g2l16(const ushort* g, ushort* l) {
    __builtin_amdgcn_global_load_lds(
        (const __attribute__((address_space(1))) unsigned int*)g,
        (__attribute__((address_space(3))) unsigned int*)l, 16, 0, 0);
}

// ---------------------------------------------------------------------------
// GEMM: C[M,N] = A[M,K] * B[N,K]^T + bias[N];  A,B bf16 bits, C f32.
//
// Round-2 post-mortem: K-split cut LDS reads 25% -> dur flat at 74.8us,
// MfmaUtil flat 37%.  NOT LDS-BW-bound.  The real cost: the per-tile order
// {12 ds_reads -> lgkm0 -> barrier -> STAGE -> 32 MFMA} serializes the
// CU-wide read DRAIN (~1130cy, MFMA idle) with the MFMA cluster (~1242cy,
// LDS idle) -> ~2400cy/tile = measured 2737.
//
// This round: same sync skeleton (3-deep ring, vmcnt 12/6/0 counted waits,
// 2 raw s_barriers per tile, STAGE/swizzle/K-split/bn-stripes all verified),
// but the tile is software-pipelined at register level:
//   sub-phase p in 0..2: issue ds_reads for af-pair p+1, then 8 MFMA (pair p)
//   boundary (BEFORE last sub-phase): lgkm0; barrier; STAGE(t+3); vmcnt(12);
//     barrier; issue bf[4]+af-pair0 reads for tile t+1
//   sub-phase 3: 8 MFMA (pair 3) -- hides the 6-read drain of tile t+1
// Read drain now overlaps MFMA everywhere; register ping-pong (2 af-pairs +
// 2 bf sets = 48 VGPR live, same as the old single-buffered frag set).
// ---------------------------------------------------------------------------
#define BK     64
#define BM     256
#define BN     128
#define NT     (IN_F / BK)        // 64 K-tiles
#define ASLOT  (BM * BK)          // 16384 ushorts = 32 KiB
#define BSLOT  (BN * BK)          //  8192 ushorts = 16 KiB
#define LDS_BYTES (3 * (ASLOT + BSLOT) * 2)   // 147456 B = 144 KiB

__global__ __launch_bounds__(512, 2) void gemm_bt_kernel(
    const ushort* __restrict__ A,
    const ushort* __restrict__ B,
    const float* __restrict__ bias,
    float* __restrict__ C)
{
    extern __shared__ ushort lds[];
    ushort* As = lds;                  // [3][ASLOT]
    ushort* Bs = lds + 3 * ASLOT;      // [3][BSLOT]

    const int tid  = threadIdx.x;
    const int lane = tid & 63;
    const int wid  = tid >> 6;         // 0..7
    const int g    = wid >> 2;         // K-group: 0 -> k[0,32), 1 -> k[32,64)
    const int w2   = wid & 3;          // spatial wave 2x2
    const int wm   = (w2 >> 1) << 7;   // 0/128
    const int wn   = (w2 & 1) << 6;    // 0/64
    const int fm   = lane & 15;
    const int q    = lane >> 4;        // 0..3

    // XCD-aware swizzle, bn-stripes (verified round-2: FETCH 139->82 MB)
    const int bid = blockIdx.x;
    const int jj  = bid >> 3;                  // 0..31
    const int bn  = (bid & 7) * 4 + (jj & 3);  // 0..31
    const int bm  = jj >> 2;                   // 0..7

    // staging: wave-instr covers 64 consecutive 16B chunks (8 rows x 8 segs);
    // lane = (row&7)*8 + pseg; global source segment = pseg ^ (row&7).
    const int gcol = (((lane & 7) ^ (lane >> 3)) << 3);

    const ushort* gA = A + (size_t)(bm * BM) * IN_F;
    const ushort* gB = B + (size_t)(bn * BN) * IN_F;

    // frag base addresses (swizzled; sa is wave-invariant across tiles)
    const int sa = (((q + 4 * g) & 7) ^ (fm & 7)) << 3;
    const ushort* Abase = As + (wm + fm) * BK + sa;   // + sl*ASLOT + i*16*BK
    const ushort* Bbase = Bs + (wn + fm) * BK + sa;   // + sl*BSLOT + j*16*BK

    floatx4 acc[8][4];
#pragma unroll
    for (int i = 0; i < 8; i++)
#pragma unroll
        for (int j = 0; j < 4; j++)
            acc[i][j] = (floatx4){0.f, 0.f, 0.f, 0.f};

    short8 bf[4], bfn[4];   // current / next-tile B frags
    short8 afc[2], afn[2];  // current / next af pair

    // 6 VMEM instrs per wave per tile (vmcnt counts these).
#define STAGE(k0v, sl)                                                        \
    {                                                                         \
        _Pragma("unroll")                                                     \
        for (int u = 0; u < 4; u++) {                                         \
            const int cb = ((u << 3) | wid) << 6;                             \
            const int r  = (cb >> 3) + (lane >> 3);                           \
            g2l16(gA + (size_t)r * IN_F + (k0v) + gcol,                       \
                  As + (sl) * ASLOT + cb * 8 + lane * 8);                     \
        }                                                                     \
        _Pragma("unroll")                                                     \
        for (int u = 0; u < 2; u++) {                                         \
            const int cb = ((u << 3) | wid) << 6;                             \
            const int r  = (cb >> 3) + (lane >> 3);                           \
            g2l16(gB + (size_t)r * IN_F + (k0v) + gcol,                       \
                  Bs + (sl) * BSLOT + cb * 8 + lane * 8);                     \
        }                                                                     \
    }

#define LOADA2(p_, sl)                                                        \
    afn[0] = *(const short8*)(Abase + (sl) * ASLOT + (2 * (p_)    ) * (16 * BK)); \
    afn[1] = *(const short8*)(Abase + (sl) * ASLOT + (2 * (p_) + 1) * (16 * BK));

#define LOADB4(sl)                                                            \
    _Pragma("unroll")                                                         \
    for (int j = 0; j < 4; j++)                                               \
        bfn[j] = *(const short8*)(Bbase + (sl) * BSLOT + j * (16 * BK));

#define MFMA8(p_)                                                             \
    __builtin_amdgcn_s_setprio(1);                                            \
    _Pragma("unroll")                                                         \
    for (int r = 0; r < 2; r++)                                               \
        _Pragma("unroll")                                                     \
        for (int j = 0; j < 4; j++)                                           \
            acc[2 * (p_) + r][j] = __builtin_amdgcn_mfma_f32_16x16x32_bf16(   \
                afc[r], bf[j], acc[2 * (p_) + r][j], 0, 0, 0);                \
    __builtin_amdgcn_s_setprio(0);

    // sub-phase p: issue reads for pair p+1, compute pair p
#define SUBPH(p_, sl)                                                         \
    {                                                                         \
        LOADA2((p_) + 1, sl);                                                 \
        __builtin_amdgcn_sched_barrier(0);                                    \
        MFMA8(p_);                                                            \
        afc[0] = afn[0]; afc[1] = afn[1];                                     \
    }

#define COPY_NEXT()                                                           \
    bf[0] = bfn[0]; bf[1] = bfn[1]; bf[2] = bfn[2]; bf[3] = bfn[3];           \
    afc[0] = afn[0]; afc[1] = afn[1];

    // prologue: fill the 3-deep ring (18 loads/wave in flight)
    STAGE(0 * BK, 0);
    STAGE(1 * BK, 1);
    STAGE(2 * BK, 2);
    asm volatile("s_waitcnt vmcnt(12)" ::: "memory");   // S(0) landed
    __builtin_amdgcn_s_barrier();                       // all waves' S(0)
    LOADB4(0); LOADA2(0, 0);
    __builtin_amdgcn_sched_barrier(0);
    COPY_NEXT();

    int st   = 0;
    int kpre = 3 * BK;
#pragma unroll 1
    for (int t = 0; t <= NT - 4; ++t) {     // t = 0..60, stages tiles 3..63
        const int stn = (st == 2) ? 0 : st + 1;
        SUBPH(0, st);
        SUBPH(1, st);
        SUBPH(2, st);
        // boundary before last sub-phase: free slot st, stage t+3, open t+1
        asm volatile("s_waitcnt lgkmcnt(0)" ::: "memory");  // slot-st reads done
        __builtin_amdgcn_s_barrier();
        STAGE(kpre, st);
        asm volatile("s_waitcnt vmcnt(12)" ::: "memory");   // S(t+1) landed
        __builtin_amdgcn_s_barrier();
        LOADB4(stn); LOADA2(0, stn);
        __builtin_amdgcn_sched_barrier(0);
        MFMA8(3);                            // hides the 6-read drain
        COPY_NEXT();
        st = stn;
        kpre += BK;
    }
    // t = 61 (slot 1): no stage; slot2 needs S(62): vmcnt(6)
    SUBPH(0, 1); SUBPH(1, 1); SUBPH(2, 1);
    asm volatile("s_waitcnt vmcnt(6)" ::: "memory");
    __builtin_amdgcn_s_barrier();
    LOADB4(2); LOADA2(0, 2);
    __builtin_amdgcn_sched_barrier(0);
    MFMA8(3);
    COPY_NEXT();
    // t = 62 (slot 2): slot0 needs S(63): vmcnt(0)
    SUBPH(0, 2); SUBPH(1, 2); SUBPH(2, 2);
    asm volatile("s_waitcnt vmcnt(0)" ::: "memory");
    __builtin_amdgcn_s_barrier();
    LOADB4(0); LOADA2(0, 0);
    __builtin_amdgcn_sched_barrier(0);
    MFMA8(3);
    COPY_NEXT();
    // t = 63 (slot 0): final tile, no boundary
    SUBPH(0, 0); SUBPH(1, 0); SUBPH(2, 0);
    MFMA8(3);

#undef STAGE
#undef LOADA2
#undef LOADB4
#undef MFMA8
#undef SUBPH
#undef COPY_NEXT

    // -----------------------------------------------------------------------
    // K-split reduction: group1 parks its partials in LDS (ring memory dead),
    // group0 adds them, applies bias, stores C.
    // -----------------------------------------------------------------------
    __syncthreads();                       // all ring reads done before reuse
    floatx4* red = (floatx4*)lds;          // 128 KiB used of 144
    if (g == 1) {
#pragma unroll
        for (int i = 0; i < 8; i++)
#pragma unroll
            for (int j = 0; j < 4; j++)
                red[(size_t)(w2 * 32 + i * 4 + j) * 64 + lane] = acc[i][j];
    }
    __syncthreads();
    if (g == 0) {
        // epilogue: C/D layout col = lane&15, row = (lane>>4)*4 + reg  [m89]
        const int cn = lane & 15;
        const int cm = (lane >> 4) << 2;
        float bv[4];
#pragma unroll
        for (int j = 0; j < 4; j++)
            bv[j] = bias[bn * BN + wn + j * 16 + cn];
#pragma unroll
        for (int i = 0; i < 8; i++) {
#pragma unroll
            for (int j = 0; j < 4; j++) {
                floatx4 p = red[(size_t)(w2 * 32 + i * 4 + j) * 64 + lane];
#pragma unroll
                for (int r = 0; r < 4; r++) acc[i][j][r] += p[r];
            }
#pragma unroll
            for (int r = 0; r < 4; r++) {
                int m = bm * BM + wm + i * 16 + cm + r;
                float* crow = C + (size_t)m * OUT_F + bn * BN + wn + cn;
#pragma unroll
                for (int j = 0; j < 4; j++)
                    crow[j * 16] = acc[i][j][r] + bv[j];
            }
        }
    }
}

extern "C" void kernel_launch(void* const* d_in, const int* in_sizes, int n_in,
                              void* d_out, int out_size, void* d_ws, size_t ws_size,
                              hipStream_t stream) {
    const float* x    = (const float*)d_in[0];   // [2048, 4096]
    const float* seed = (const float*)d_in[1];   // [4096, 4096]
    const float* da   = (const float*)d_in[2];   // [20]
    const float* db   = (const float*)d_in[3];   // [20]
    const float* bias = (const float*)d_in[4];   // [4096]
    float* out        = (float*)d_out;           // [2048, 4096]

    ushort* w_bf = (ushort*)d_ws;                      // 32 MiB
    ushort* x_bf = w_bf + (size_t)OUT_F * IN_F;        // 16 MiB

    // allow 144 KiB dynamic LDS (one-time host-side attribute; not a stream op)
    static bool lds_attr_set = false;
    if (!lds_attr_set) {
        hipFuncSetAttribute(reinterpret_cast<const void*>(gemm_bt_kernel),
                            hipFuncAttributeMaxDynamicSharedMemorySize,
                            LDS_BYTES);
        lds_attr_set = true;
    }

    transcribe_fused_kernel<<<WBLOCKS + XBLOCKS, 256, 0, stream>>>(
        (const float4*)seed, (const float4*)x, da, db,
        (short8*)w_bf, (short8*)x_bf);

    gemm_bt_kernel<<<dim3(32 * 8), dim3(512), LDS_BYTES, stream>>>(
        x_bf, w_bf, bias, out);
}